// Round 1
// 643.658 us; speedup vs baseline: 1.0023x; 1.0023x over previous
//
#include <hip/hip_runtime.h>

#define HCH 512      // channels
#define LSEQ 4096    // sequence length
#define NB 32        // batch
#define KW 3         // conv kernel width
#define KDIM 1536    // HCH*KW, GEMM K
#define SPAD 1408    // padded chunk slots per sequence (max 1365), 11*128
#define INVS 0.9999950000374997f  // 1/sqrt(1+1e-5)
#define NT 24        // conv GEMM K-steps of 64 (3 k-slices x 8 ci-chunks)

typedef __attribute__((ext_vector_type(8))) short bf16x8;
typedef __attribute__((ext_vector_type(4))) float f32x4;

__device__ inline unsigned short f2bf(float f) {
  unsigned int u = __float_as_uint(f);
  u += 0x7fffu + ((u >> 16) & 1u);
  return (unsigned short)(u >> 16);
}

__device__ inline void gl_lds16(const void* g, void* l) {
  __builtin_amdgcn_global_load_lds(
      (const __attribute__((address_space(1))) void*)g,
      (__attribute__((address_space(3))) void*)l, 16, 0, 0);
}

// ---- fused prep: zero zeropage+partial, chunk prefix sum, weight transpose
__global__ void prep_all(const float* __restrict__ w1, const float* __restrict__ w2,
                         const float* __restrict__ pw, unsigned short* __restrict__ wt,
                         const int* __restrict__ seq_lens, int* __restrict__ cum,
                         float* __restrict__ pz, int nz) {
  int idx = blockIdx.x * 256 + threadIdx.x;
  if (idx < nz) pz[idx] = 0.f;
  if (idx == 0) {
    int acc = 0;
    for (int b = 0; b < NB; b++) {
      cum[b] = acc;
      acc += (seq_lens[b] - KW) / KW + 1;
    }
  }
  if (idx < 3 * HCH * KDIM) {
    int which = idx / (HCH * KDIM);
    int r = idx % (HCH * KDIM);
    int c = r / KDIM;
    int rem = r % KDIM;
    int k = rem / HCH, ci = rem % HCH;
    const float* src = (which == 0) ? w1 : ((which == 1) ? w2 : pw);
    wt[idx] = f2bf(src[c * KDIM + ci * KW + k]);
  }
}

// ---- layer 0: 1->512 conv + relu + scale/shift, fp32 in, bf16 (b,l,C) out
__global__ void layer0(const float* __restrict__ x, const float* __restrict__ w0,
                       const float* __restrict__ b0, const float* __restrict__ g0,
                       const float* __restrict__ be0, unsigned short* __restrict__ h0,
                       const int* __restrict__ seq_q) {
  int tid = threadIdx.x;
  int wave = tid >> 6, lane = tid & 63;
  int pos0 = (blockIdx.x * 4 + wave) * 8;      // flattened (b_local*4096 + l)
  int l0 = pos0 & (LSEQ - 1);
  if (l0 >= seq_q[pos0 >> 12] + 2) return;     // h0 needed only for l <= slen+1
  int c0 = lane * 8;

  float w[24], bb[8], gg[8], ee[8];
  for (int v = 0; v < 6; v++)
    *reinterpret_cast<float4*>(w + v * 4) = *reinterpret_cast<const float4*>(w0 + c0 * 3 + v * 4);
  for (int v = 0; v < 2; v++) {
    *reinterpret_cast<float4*>(bb + v * 4) = *reinterpret_cast<const float4*>(b0 + c0 + v * 4);
    *reinterpret_cast<float4*>(gg + v * 4) = *reinterpret_cast<const float4*>(g0 + c0 + v * 4);
    *reinterpret_cast<float4*>(ee + v * 4) = *reinterpret_cast<const float4*>(be0 + c0 + v * 4);
  }
  for (int c = 0; c < 8; c++) gg[c] *= INVS;

  const float* xb = x + (size_t)(pos0 - l0);   // batch base
  for (int pp = 0; pp < 8; pp++) {
    int l = l0 + pp;
    float xm1 = (l > 0) ? xb[l - 1] : 0.f;
    float xc = xb[l];
    float xp1 = (l < LSEQ - 1) ? xb[l + 1] : 0.f;
    unsigned int o[4];
    for (int pq = 0; pq < 4; pq++) {
      unsigned int lo = 0, hi = 0;
      for (int s = 0; s < 2; s++) {
        int c = pq * 2 + s;
        float y = w[c * 3] * xm1 + w[c * 3 + 1] * xc + w[c * 3 + 2] * xp1 + bb[c];
        y = fmaxf(y, 0.f);
        unsigned int u = f2bf(gg[c] * y + ee[c]);
        if (s == 0) lo = u; else hi = u;
      }
      o[pq] = lo | (hi << 16);
    }
    uint4 v4; v4.x = o[0]; v4.y = o[1]; v4.z = o[2]; v4.w = o[3];
    *reinterpret_cast<uint4*>(h0 + (size_t)(pos0 + pp) * HCH + c0) = v4;
  }
}

// ---- conv layer as 256x256 8-phase pipelined GEMM (T1+T2+T3/T4+T5) -------
// K-step t of 64: k = t>>3, ci0 = (t&7)*64; B tile = contiguous 256-pos
// window of h shifted by k-1 (no halo rows).  LDS: 2 dbuf x {A0,A1,B0,B1}
// panels of [128 rows][64 ci] bf16, linear for global_load_lds; T2 swizzle
// baked into per-lane SOURCE slot (slot ^= row&7) and undone on ds_read.
// Counted waits: vmcnt(6) after phase 2, vmcnt(2) after phase 4 (derived:
// issue order per K-step is B0,B1 @p1 / A0 @p2 / A1 @p3, one step ahead).
#define STAGE_A(Mh, nbuf, tn)                                               \
  { char* d_ = ldsc + ((nbuf)*4 + (Mh)) * 16384 + w * 1024;                 \
    gl_lds16(aSrc[Mh][0] + (tn)*64, d_);                                    \
    gl_lds16(aSrc[Mh][1] + (tn)*64, d_ + 8192); }

#define STAGE_B(Nh, nbuf, tn)                                               \
  { int k_ = (tn) >> 3, ci0_ = ((tn) & 7) << 6;                             \
    int p0_ = bRow[Nh][0] + k_, p1_ = bRow[Nh][1] + k_;                     \
    const unsigned short* s0_ = ((unsigned)p0_ < 4096u)                     \
        ? hin + hb + (size_t)p0_ * HCH + ci0_ + sslot8 : zp + sslot8;       \
    const unsigned short* s1_ = ((unsigned)p1_ < 4096u)                     \
        ? hin + hb + (size_t)p1_ * HCH + ci0_ + sslot8 : zp + sslot8;       \
    char* d_ = ldsc + ((nbuf)*4 + 2 + (Nh)) * 16384 + w * 1024;             \
    gl_lds16(s0_, d_); gl_lds16(s1_, d_ + 8192); }

#define LOAD_AF(Mh, buf)                                                    \
  _Pragma("unroll") for (int i_ = 0; i_ < 4; ++i_)                          \
  _Pragma("unroll") for (int s_ = 0; s_ < 2; ++s_)                          \
    af[i_][s_] = *reinterpret_cast<const bf16x8*>(                          \
        ldsb + ((buf)*4 + (Mh)) * 8192 + (wm + i_*16 + mr) * 64 +           \
        (((s_*4 + quad) ^ (mr & 7)) << 3));

#define LOAD_BF(Nh, buf)                                                    \
  _Pragma("unroll") for (int j_ = 0; j_ < 2; ++j_)                          \
  _Pragma("unroll") for (int s_ = 0; s_ < 2; ++s_)                          \
    bfv[j_][s_] = *reinterpret_cast<const bf16x8*>(                         \
        ldsb + ((buf)*4 + 2 + (Nh)) * 8192 + (wn + j_*16 + mr) * 64 +       \
        (((s_*4 + quad) ^ (mr & 7)) << 3));

#define MFMA_Q(Mh, Nh)                                                      \
  __builtin_amdgcn_s_setprio(1);                                            \
  _Pragma("unroll") for (int i_ = 0; i_ < 4; ++i_)                          \
  _Pragma("unroll") for (int j_ = 0; j_ < 2; ++j_)                          \
  _Pragma("unroll") for (int s_ = 0; s_ < 2; ++s_)                          \
    acc[(Mh)*4 + i_][(Nh)*2 + j_] = __builtin_amdgcn_mfma_f32_16x16x32_bf16( \
        af[i_][s_], bfv[j_][s_], acc[(Mh)*4 + i_][(Nh)*2 + j_], 0, 0, 0);   \
  __builtin_amdgcn_s_setprio(0);

#define BARRIER { asm volatile("" ::: "memory");                            \
                  __builtin_amdgcn_s_barrier();                             \
                  asm volatile("" ::: "memory"); }
#define WAITV(n) asm volatile("s_waitcnt vmcnt(" #n ")" ::: "memory");

__global__ __launch_bounds__(512, 2) void conv_gemm8(
    const unsigned short* __restrict__ hin,   // (nb,L,C) bf16
    const unsigned short* __restrict__ wT,    // (512, 1536) bf16 A-layout
    const float* __restrict__ bconv, const float* __restrict__ g,
    const float* __restrict__ be,
    unsigned short* __restrict__ hout,        // (nb,L,C) bf16
    const unsigned short* __restrict__ zp,
    const int* __restrict__ seq_q, int margin) {
  __shared__ unsigned short ldsb[8 * 8192];   // 8 panels [128][64], 128 KiB

  // T1: bijective XCD-chunk swizzle; pairs (x=0,1 of same tile) stay on one XCD
  int f = blockIdx.x;
  int cpx = gridDim.x >> 3;                   // gridDim.x % 8 == 0 by launch
  int s = (f & 7) * cpx + (f >> 3);
  int cm = (s & 1) << 8;                      // out-channel tile: 0 or 256
  int y = s >> 1;
  int b = y >> 4;                             // batch-local
  int l0 = (y & 15) << 8;                     // 256-position tile
  int limit = seq_q[b] + margin;              // outputs needed for n < limit
  if (l0 >= limit) return;                    // block-uniform, pre-barrier

  const size_t hb = (size_t)b * LSEQ * HCH;
  int tid = threadIdx.x;
  int w = tid >> 6, lane = tid & 63;
  int quad = lane >> 4, mr = lane & 15;
  int wm = (w >> 2) << 6;                     // 0/64 within A half
  int wn = (w & 3) << 5;                      // 0/32/64/96 within B half
  int srow = tid >> 3;                        // staging row 0..63 within group
  int sslot8 = (((tid & 7) ^ (srow & 7)) << 3);  // swizzled src offset (shorts)

  // A sources [Mh][row-group]: wT row = channel, contiguous K
  const unsigned short* aSrc[2][2];
#pragma unroll
  for (int Mh = 0; Mh < 2; ++Mh)
#pragma unroll
    for (int g2 = 0; g2 < 2; ++g2)
      aSrc[Mh][g2] = wT + (size_t)(cm + Mh*128 + g2*64 + srow) * KDIM + sslot8;
  // B position bases (for k=0): window starts at l0-1
  int bRow[2][2];
#pragma unroll
  for (int Nh = 0; Nh < 2; ++Nh)
#pragma unroll
    for (int g2 = 0; g2 < 2; ++g2)
      bRow[Nh][g2] = l0 - 1 + Nh*128 + g2*64 + srow;

  f32x4 acc[8][4] = {};
  char* ldsc = (char*)ldsb;

  // prologue: stage K-step 0 into buf 0; force B0,B1,A0 landed (A1 in flight)
  STAGE_B(0, 0, 0); STAGE_B(1, 0, 0); STAGE_A(0, 0, 0); STAGE_A(1, 0, 0);
  WAITV(2);
  __builtin_amdgcn_s_barrier();
  asm volatile("" ::: "memory");

#pragma unroll 2
  for (int t = 0; t < NT; ++t) {
    int buf = t & 1, nbuf = buf ^ 1;
    int tn = (t + 1 < NT) ? t + 1 : t;        // last iter: harmless re-stage
    bf16x8 af[4][2], bfv[2][2];
    // phase 1: quadrant (0,0); issue B0,B1 of next K-step
    LOAD_AF(0, buf); LOAD_BF(0, buf);
    STAGE_B(0, nbuf, tn); STAGE_B(1, nbuf, tn);
    BARRIER;
    MFMA_Q(0, 0);
    BARRIER;
    // phase 2: quadrant (0,1); issue A0(next); force A1(cur) landed
    LOAD_BF(1, buf);
    STAGE_A(0, nbuf, tn);
    BARRIER;
    MFMA_Q(0, 1);
    WAITV(6);
    BARRIER;
    // phase 3: quadrant (1,0); issue A1(next)
    LOAD_AF(1, buf); LOAD_BF(0, buf);
    STAGE_A(1, nbuf, tn);
    BARRIER;
    MFMA_Q(1, 0);
    BARRIER;
    // phase 4: quadrant (1,1); force B0,B1,A0(next) landed
    LOAD_BF(1, buf);
    BARRIER;
    MFMA_Q(1, 1);
    WAITV(2);
    BARRIER;
  }

  // epilogue: relu(acc + b) * g*inv + be -> bf16; C/D: col=lane&15, row=quad*4+r
#pragma unroll
  for (int ai = 0; ai < 8; ++ai) {
    int Mh = ai >> 2, i = ai & 3;
    int c = cm + Mh*128 + wm + i*16 + quad*4;
    f32x4 bc = *reinterpret_cast<const f32x4*>(bconv + c);
    f32x4 gg = *reinterpret_cast<const f32x4*>(g + c);
    f32x4 bb = *reinterpret_cast<const f32x4*>(be + c);
#pragma unroll
    for (int aj = 0; aj < 4; ++aj) {
      int Nh = aj >> 1, j = aj & 1;
      int n = l0 + Nh*128 + wn + j*16 + (lane & 15);
      if (n >= limit) continue;
      unsigned long long pack = 0;
#pragma unroll
      for (int r = 0; r < 4; ++r) {
        float yv = acc[ai][aj][r] + bc[r];
        yv = fmaxf(yv, 0.f);
        unsigned long long u = f2bf(gg[r] * INVS * yv + bb[r]);
        pack |= u << (16 * r);
      }
      *reinterpret_cast<unsigned long long*>(hout + hb + (size_t)n * HCH + c) = pack;
    }
  }
}

// ---- chunk einsum GEMM + fused head (unchanged this round) ---------------
__global__ __launch_bounds__(256) void chunk_gemm(
    const unsigned short* __restrict__ h2,    // (nb,L,C) bf16
    const unsigned short* __restrict__ wTp,   // (512,1536) bf16 A-layout
    const float* __restrict__ pb, const float* __restrict__ fw,
    const int* __restrict__ seq_q,            // seq_lens for this pass's batches
    const int* __restrict__ cum_q,            // global chunk base per batch
    float* __restrict__ partial,
    const unsigned short* __restrict__ zp) {
  __shared__ unsigned short As[3 * 128 * 32]; // [t][c][ci]
  __shared__ unsigned short Bs[384 * 32];     // [row=p-3*s_base][ci]

  int tid = threadIdx.x;
  int wave = tid >> 6, lane = tid & 63;
  int cm = blockIdx.x * 128;
  int b = blockIdx.y / (SPAD / 128);          // batch-local (uniform per block)
  int s_base = (blockIdx.y % (SPAD / 128)) * 128;
  int slen = seq_q[b];
  if (3 * s_base + KW > slen) return;
  int p_base = 3 * s_base;
  int wm = (wave >> 1) * 64;
  int wn = (wave & 1) * 64;
  const size_t hb = (size_t)b * LSEQ * HCH;

  f32x4 acc[4][4] = {};

  int lr = lane >> 2, lc = (lane & 3) * 8;

  const unsigned short* bptr[6];
  const unsigned short* aptr[6];
  unsigned aoff[6];
  for (int t = 0; t < 6; t++) {
    int c = wave * 6 + t;
    int p = p_base + c * 16 + lr;
    bptr[t] = (p < LSEQ) ? (h2 + hb + (size_t)p * HCH + lc) : (zp + lc);
    int k = c >> 3, c8 = c & 7;
    aptr[t] = wTp + (size_t)(cm + c8 * 16 + lr) * KDIM + k * HCH + lc;
    aoff[t] = (unsigned)(k * 4096 + c8 * 512) * 2;
  }

  for (int it = 0; it < 16; it++) {
    int ci0 = it * 32;
    for (int t = 0; t < 6; t++) {
      gl_lds16(aptr[t] + ci0, (char*)As + aoff[t]);
      gl_lds16(bptr[t] + ci0, (char*)Bs + (wave * 6 + t) * 1024);
    }
    __syncthreads();

    int quad = lane >> 4, mr = lane & 15;
    for (int t = 0; t < 3; t++) {
      bf16x8 af[4], bfr[4];
      for (int i = 0; i < 4; i++)
        af[i] = *reinterpret_cast<const bf16x8*>(As + t * 4096 + (wm + i * 16 + mr) * 32 + quad * 8);
      for (int j = 0; j < 4; j++)
        bfr[j] = *reinterpret_cast<const bf16x8*>(Bs + (3 * (wn + j * 16 + mr) + t) * 32 + quad * 8);
      for (int i = 0; i < 4; i++)
        for (int j = 0; j < 4; j++)
          acc[i][j] = __builtin_amdgcn_mfma_f32_16x16x32_bf16(af[i], bfr[j], acc[i][j], 0, 0, 0);
    }
    __syncthreads();
  }

  // fused head: per column s, sum relu(z+pb)*fw over this block's 128 channels
  int quad = lane >> 4, nn = lane & 15;
  for (int j = 0; j < 4; j++) {
    float s = 0.f;
    for (int i = 0; i < 4; i++) {
      int c = cm + wm + i * 16 + quad * 4;
      f32x4 pbv = *reinterpret_cast<const f32x4*>(pb + c);
      f32x4 fwv = *reinterpret_cast<const f32x4*>(fw + c);
      for (int r = 0; r < 4; r++) {
        float z = acc[i][j][r] + pbv[r];
        z = fmaxf(z, 0.f);
        s += z * fwv[r];
      }
    }
    s += __shfl_xor(s, 16, 64);
    s += __shfl_xor(s, 32, 64);
    if (quad == 0) {
      int sc = s_base + wn + j * 16 + nn;
      if (3 * sc + KW <= slen) atomicAdd(partial + cum_q[b] + sc, s);
    }
  }
}

// ---- final: sigmoid(partial + fb) ----------------------------------------
__global__ void finalize(const float* __restrict__ partial, const float* __restrict__ fb,
                         float* __restrict__ out, int n) {
  int i = blockIdx.x * 256 + threadIdx.x;
  if (i < n) {
    float t = partial[i] + fb[0];
    out[i] = 1.f / (1.f + expf(-t));
  }
}

extern "C" void kernel_launch(void* const* d_in, const int* in_sizes, int n_in,
                              void* d_out, int out_size, void* d_ws, size_t ws_size,
                              hipStream_t stream) {
  (void)in_sizes; (void)n_in;
  const float* x   = (const float*)d_in[0];
  const float* w0  = (const float*)d_in[1];
  const float* b0  = (const float*)d_in[2];
  const float* g0  = (const float*)d_in[3];
  const float* be0 = (const float*)d_in[4];
  const float* w1  = (const float*)d_in[5];
  const float* b1  = (const float*)d_in[6];
  const float* g1  = (const float*)d_in[7];
  const float* be1 = (const float*)d_in[8];
  const float* w2  = (const float*)d_in[9];
  const float* b2  = (const float*)d_in[10];
  const float* g2  = (const float*)d_in[11];
  const float* be2 = (const float*)d_in[12];
  const float* pw  = (const float*)d_in[13];
  const float* pb  = (const float*)d_in[14];
  const float* fw  = (const float*)d_in[15];
  const float* fb  = (const float*)d_in[16];
  const int* seq_lens = (const int*)d_in[17];

  char* ws = (char*)d_ws;
  unsigned short* zeropage = (unsigned short*)ws;          // 4096 B, zeroed
  float* partial = (float*)(ws + 4096);                    // out_size floats, zeroed
  size_t off = 4096 + (size_t)out_size * 4;
  off = (off + 255) & ~(size_t)255;
  int* cum = (int*)(ws + off);                             // NB ints
  off += NB * 4;
  off = (off + 255) & ~(size_t)255;
  unsigned short* wt = (unsigned short*)(ws + off);        // 3 x 512 x 1536 bf16
  off += (size_t)3 * HCH * KDIM * 2;
  off = (off + 255) & ~(size_t)255;
  size_t fixed = off;

  // pick largest power-of-two batches-per-pass whose 2 ping-pong buffers fit
  const size_t per_batch = (size_t)LSEQ * HCH * 2;         // 4 MiB
  int nb_pass = NB;
  while (nb_pass > 1 && fixed + 2 * per_batch * (size_t)nb_pass > ws_size)
    nb_pass >>= 1;
  unsigned short* h0 = (unsigned short*)(ws + fixed);
  unsigned short* h1 = h0 + (size_t)nb_pass * LSEQ * HCH;

  int nzero = 1024 + out_size;   // zeropage (1024 floats) + partial
  prep_all<<<(3 * HCH * KDIM) / 256, 256, 0, stream>>>(w1, w2, pw, wt, seq_lens, cum,
                                                       (float*)ws, nzero);

  int npass = NB / nb_pass;
  for (int q = 0; q < npass; q++) {
    const float* xq = x + (size_t)q * nb_pass * LSEQ;
    const int* sq = seq_lens + q * nb_pass;
    int nwg = nb_pass * 32;                  // 2 M-tiles x 16 N-tiles per batch
    layer0<<<nb_pass * (LSEQ / 32), 256, 0, stream>>>(xq, w0, b0, g0, be0, h0, sq);
    conv_gemm8<<<nwg, 512, 0, stream>>>(h0, wt, b1, g1, be1, h1, zeropage, sq, 1);
    conv_gemm8<<<nwg, 512, 0, stream>>>(h1, wt + (size_t)HCH * KDIM, b2, g2, be2, h0,
                                        zeropage, sq, 0);
    chunk_gemm<<<dim3(4, nb_pass * (SPAD / 128)), 256, 0, stream>>>(
        h0, wt + (size_t)2 * HCH * KDIM, pb, fw,
        sq, cum + q * nb_pass, partial, zeropage);
  }
  finalize<<<(out_size + 255) / 256, 256, 0, stream>>>(partial, fb, (float*)d_out, out_size);
}

// Round 2
// 614.400 us; speedup vs baseline: 1.0501x; 1.0476x over previous
//
#include <hip/hip_runtime.h>

#define HCH 512      // channels
#define LSEQ 4096    // sequence length
#define NB 32        // batch
#define KW 3         // conv kernel width
#define KDIM 1536    // HCH*KW, GEMM K
#define SPAD 1408    // padded chunk slots per sequence (max 1365), 11*128
#define INVS 0.9999950000374997f  // 1/sqrt(1+1e-5)
#define NT 24        // conv GEMM K-steps of 64 (3 k-slices x 8 ci-chunks)

typedef __attribute__((ext_vector_type(8))) short bf16x8;
typedef __attribute__((ext_vector_type(4))) float f32x4;

__device__ inline unsigned short f2bf(float f) {
  unsigned int u = __float_as_uint(f);
  u += 0x7fffu + ((u >> 16) & 1u);
  return (unsigned short)(u >> 16);
}

__device__ inline void gl_lds16(const void* g, void* l) {
  __builtin_amdgcn_global_load_lds(
      (const __attribute__((address_space(1))) void*)g,
      (__attribute__((address_space(3))) void*)l, 16, 0, 0);
}

// ---- fused prep: zero zeropage+partial, chunk prefix sum, weight transpose
__global__ void prep_all(const float* __restrict__ w1, const float* __restrict__ w2,
                         const float* __restrict__ pw, unsigned short* __restrict__ wt,
                         const int* __restrict__ seq_lens, int* __restrict__ cum,
                         float* __restrict__ pz, int nz) {
  int idx = blockIdx.x * 256 + threadIdx.x;
  if (idx < nz) pz[idx] = 0.f;
  if (idx == 0) {
    int acc = 0;
    for (int b = 0; b < NB; b++) {
      cum[b] = acc;
      acc += (seq_lens[b] - KW) / KW + 1;
    }
  }
  if (idx < 3 * HCH * KDIM) {
    int which = idx / (HCH * KDIM);
    int r = idx % (HCH * KDIM);
    int c = r / KDIM;
    int rem = r % KDIM;
    int k = rem / HCH, ci = rem % HCH;
    const float* src = (which == 0) ? w1 : ((which == 1) ? w2 : pw);
    wt[idx] = f2bf(src[c * KDIM + ci * KW + k]);
  }
}

// ---- layer 0: 1->512 conv + relu + scale/shift, fp32 in, bf16 (b,l,C) out
__global__ void layer0(const float* __restrict__ x, const float* __restrict__ w0,
                       const float* __restrict__ b0, const float* __restrict__ g0,
                       const float* __restrict__ be0, unsigned short* __restrict__ h0,
                       const int* __restrict__ seq_q) {
  int tid = threadIdx.x;
  int wave = tid >> 6, lane = tid & 63;
  int pos0 = (blockIdx.x * 4 + wave) * 8;      // flattened (b_local*4096 + l)
  int l0 = pos0 & (LSEQ - 1);
  if (l0 >= seq_q[pos0 >> 12] + 2) return;     // h0 needed only for l <= slen+1
  int c0 = lane * 8;

  float w[24], bb[8], gg[8], ee[8];
  for (int v = 0; v < 6; v++)
    *reinterpret_cast<float4*>(w + v * 4) = *reinterpret_cast<const float4*>(w0 + c0 * 3 + v * 4);
  for (int v = 0; v < 2; v++) {
    *reinterpret_cast<float4*>(bb + v * 4) = *reinterpret_cast<const float4*>(b0 + c0 + v * 4);
    *reinterpret_cast<float4*>(gg + v * 4) = *reinterpret_cast<const float4*>(g0 + c0 + v * 4);
    *reinterpret_cast<float4*>(ee + v * 4) = *reinterpret_cast<const float4*>(be0 + c0 + v * 4);
  }
  for (int c = 0; c < 8; c++) gg[c] *= INVS;

  const float* xb = x + (size_t)(pos0 - l0);   // batch base
  for (int pp = 0; pp < 8; pp++) {
    int l = l0 + pp;
    float xm1 = (l > 0) ? xb[l - 1] : 0.f;
    float xc = xb[l];
    float xp1 = (l < LSEQ - 1) ? xb[l + 1] : 0.f;
    unsigned int o[4];
    for (int pq = 0; pq < 4; pq++) {
      unsigned int lo = 0, hi = 0;
      for (int s = 0; s < 2; s++) {
        int c = pq * 2 + s;
        float y = w[c * 3] * xm1 + w[c * 3 + 1] * xc + w[c * 3 + 2] * xp1 + bb[c];
        y = fmaxf(y, 0.f);
        unsigned int u = f2bf(gg[c] * y + ee[c]);
        if (s == 0) lo = u; else hi = u;
      }
      o[pq] = lo | (hi << 16);
    }
    uint4 v4; v4.x = o[0]; v4.y = o[1]; v4.z = o[2]; v4.w = o[3];
    *reinterpret_cast<uint4*>(h0 + (size_t)(pos0 + pp) * HCH + c0) = v4;
  }
}

// ---- conv layer as 256x256 GEMM, ONE barrier per K-step ------------------
// K-step t of 64: k = t>>3, ci0 = (t&7)*64; B tile = contiguous 256-pos
// window of h shifted by k-1.  LDS: 2 dbuf x {A0,A1,B0,B1} panels of
// [128 rows][64 ci] bf16, linear for global_load_lds; T2 swizzle baked into
// per-lane SOURCE slot (slot ^= row&7) and undone on ds_read.
// Hazard analysis for 1 barrier/K-step: all step-t reads hit buf, all
// stage-writes hit nbuf; a wave at barrier(t) has retired its t-1 ds_reads
// (MFMAs consumed them).  vmcnt(4) @top = A(t) landed (A staged first);
// vmcnt(8) after issuing 8 next-step stages = B(t) landed.  Cover for both
// is a full K-step (~2500 cy) >> L2/HBM latency.
#define STAGE_A(Mh, nbuf, tn)                                               \
  { char* d_ = ldsc + ((nbuf)*4 + (Mh)) * 16384 + w * 1024;                 \
    gl_lds16(aSrc[Mh][0] + (tn)*64, d_);                                    \
    gl_lds16(aSrc[Mh][1] + (tn)*64, d_ + 8192); }

#define STAGE_B(Nh, nbuf, tn)                                               \
  { int k_ = (tn) >> 3, ci0_ = ((tn) & 7) << 6;                             \
    int p0_ = bRow[Nh][0] + k_, p1_ = bRow[Nh][1] + k_;                     \
    const unsigned short* s0_ = ((unsigned)p0_ < 4096u)                     \
        ? hin + hb + (size_t)p0_ * HCH + ci0_ + sslot8 : zp + sslot8;       \
    const unsigned short* s1_ = ((unsigned)p1_ < 4096u)                     \
        ? hin + hb + (size_t)p1_ * HCH + ci0_ + sslot8 : zp + sslot8;       \
    char* d_ = ldsc + ((nbuf)*4 + 2 + (Nh)) * 16384 + w * 1024;             \
    gl_lds16(s0_, d_); gl_lds16(s1_, d_ + 8192); }

#define LOAD_AF(Mh, buf)                                                    \
  _Pragma("unroll") for (int i_ = 0; i_ < 4; ++i_)                          \
  _Pragma("unroll") for (int s_ = 0; s_ < 2; ++s_)                          \
    af[i_][s_] = *reinterpret_cast<const bf16x8*>(                          \
        ldsb + ((buf)*4 + (Mh)) * 8192 + (wm + i_*16 + mr) * 64 +           \
        (((s_*4 + quad) ^ (mr & 7)) << 3));

#define LOAD_BF(Nh, buf)                                                    \
  _Pragma("unroll") for (int j_ = 0; j_ < 2; ++j_)                          \
  _Pragma("unroll") for (int s_ = 0; s_ < 2; ++s_)                          \
    bfv[Nh][j_][s_] = *reinterpret_cast<const bf16x8*>(                     \
        ldsb + ((buf)*4 + 2 + (Nh)) * 8192 + (wn + j_*16 + mr) * 64 +       \
        (((s_*4 + quad) ^ (mr & 7)) << 3));

#define MFMA_Q(Mh, Nh)                                                      \
  __builtin_amdgcn_s_setprio(1);                                            \
  _Pragma("unroll") for (int i_ = 0; i_ < 4; ++i_)                          \
  _Pragma("unroll") for (int j_ = 0; j_ < 2; ++j_)                          \
  _Pragma("unroll") for (int s_ = 0; s_ < 2; ++s_)                          \
    acc[(Mh)*4 + i_][(Nh)*2 + j_] = __builtin_amdgcn_mfma_f32_16x16x32_bf16( \
        af[i_][s_], bfv[Nh][j_][s_], acc[(Mh)*4 + i_][(Nh)*2 + j_], 0, 0, 0); \
  __builtin_amdgcn_s_setprio(0);

#define BARRIER { asm volatile("" ::: "memory");                            \
                  __builtin_amdgcn_s_barrier();                             \
                  asm volatile("" ::: "memory"); }
#define WAITV(n) asm volatile("s_waitcnt vmcnt(" #n ")" ::: "memory");

__global__ __launch_bounds__(512, 2) void conv_gemm8(
    const unsigned short* __restrict__ hin,   // (nb,L,C) bf16
    const unsigned short* __restrict__ wT,    // (512, 1536) bf16 A-layout
    const float* __restrict__ bconv, const float* __restrict__ g,
    const float* __restrict__ be,
    unsigned short* __restrict__ hout,        // (nb,L,C) bf16
    const unsigned short* __restrict__ zp,
    const int* __restrict__ seq_q, int margin) {
  __shared__ unsigned short ldsb[8 * 8192];   // 8 panels [128][64], 128 KiB

  // T1: bijective XCD-chunk swizzle; pairs (x=0,1 of same tile) stay on one XCD
  int f = blockIdx.x;
  int cpx = gridDim.x >> 3;                   // gridDim.x % 8 == 0 by launch
  int s = (f & 7) * cpx + (f >> 3);
  int cm = (s & 1) << 8;                      // out-channel tile: 0 or 256
  int y = s >> 1;
  int b = y >> 4;                             // batch-local
  int l0 = (y & 15) << 8;                     // 256-position tile
  int limit = seq_q[b] + margin;              // outputs needed for n < limit
  if (l0 >= limit) return;                    // block-uniform, pre-barrier

  const size_t hb = (size_t)b * LSEQ * HCH;
  int tid = threadIdx.x;
  int w = tid >> 6, lane = tid & 63;
  int quad = lane >> 4, mr = lane & 15;
  int wm = (w >> 2) << 6;                     // 0/64 within A half
  int wn = (w & 3) << 5;                      // 0/32/64/96 within B half
  int srow = tid >> 3;                        // staging row 0..63 within group
  int sslot8 = (((tid & 7) ^ (srow & 7)) << 3);  // swizzled src offset (shorts)

  // A sources [Mh][row-group]: wT row = channel, contiguous K
  const unsigned short* aSrc[2][2];
#pragma unroll
  for (int Mh = 0; Mh < 2; ++Mh)
#pragma unroll
    for (int g2 = 0; g2 < 2; ++g2)
      aSrc[Mh][g2] = wT + (size_t)(cm + Mh*128 + g2*64 + srow) * KDIM + sslot8;
  // B position bases (for k=0): window starts at l0-1
  int bRow[2][2];
#pragma unroll
  for (int Nh = 0; Nh < 2; ++Nh)
#pragma unroll
    for (int g2 = 0; g2 < 2; ++g2)
      bRow[Nh][g2] = l0 - 1 + Nh*128 + g2*64 + srow;

  f32x4 acc[8][4] = {};
  char* ldsc = (char*)ldsb;

  // prologue: stage K-step 0 into buf 0 (A first, then B — FIFO order matters)
  STAGE_A(0, 0, 0); STAGE_A(1, 0, 0); STAGE_B(0, 0, 0); STAGE_B(1, 0, 0);

#pragma unroll 2
  for (int t = 0; t < NT; ++t) {
    int buf = t & 1, nbuf = buf ^ 1;
    int tn = (t + 1 < NT) ? t + 1 : t;        // last iter: harmless re-stage
    bf16x8 af[4][2], bfv[2][2][2];
    WAITV(4);                                 // A(t) landed (B(t) may be in flight)
    BARRIER;                                  // all waves: buf ready, nbuf free
    // issue next K-step's 8 stages (A first, then B)
    STAGE_A(0, nbuf, tn); STAGE_A(1, nbuf, tn);
    STAGE_B(0, nbuf, tn); STAGE_B(1, nbuf, tn);
    // M-half 0 A-frags can be read now (A landed)
    LOAD_AF(0, buf);
    WAITV(8);                                 // B(t) landed (8 = t+1 stages)
    LOAD_BF(0, buf); LOAD_BF(1, buf);         // both N-halves, held in regs
    MFMA_Q(0, 0);
    MFMA_Q(0, 1);
    LOAD_AF(1, buf);                          // M-half 1 A-frags (reuse regs)
    MFMA_Q(1, 1);
    MFMA_Q(1, 0);
  }

  // epilogue: relu(acc + b) * g*inv + be -> bf16; C/D: col=lane&15, row=quad*4+r
#pragma unroll
  for (int ai = 0; ai < 8; ++ai) {
    int Mh = ai >> 2, i = ai & 3;
    int c = cm + Mh*128 + wm + i*16 + quad*4;
    f32x4 bc = *reinterpret_cast<const f32x4*>(bconv + c);
    f32x4 gg = *reinterpret_cast<const f32x4*>(g + c);
    f32x4 bb = *reinterpret_cast<const f32x4*>(be + c);
#pragma unroll
    for (int aj = 0; aj < 4; ++aj) {
      int Nh = aj >> 1, j = aj & 1;
      int n = l0 + Nh*128 + wn + j*16 + (lane & 15);
      if (n >= limit) continue;
      unsigned long long pack = 0;
#pragma unroll
      for (int r = 0; r < 4; ++r) {
        float yv = acc[ai][aj][r] + bc[r];
        yv = fmaxf(yv, 0.f);
        unsigned long long u = f2bf(gg[r] * INVS * yv + bb[r]);
        pack |= u << (16 * r);
      }
      *reinterpret_cast<unsigned long long*>(hout + hb + (size_t)n * HCH + c) = pack;
    }
  }
}

// ---- chunk einsum GEMM + fused head (unchanged this round) ---------------
__global__ __launch_bounds__(256) void chunk_gemm(
    const unsigned short* __restrict__ h2,    // (nb,L,C) bf16
    const unsigned short* __restrict__ wTp,   // (512,1536) bf16 A-layout
    const float* __restrict__ pb, const float* __restrict__ fw,
    const int* __restrict__ seq_q,            // seq_lens for this pass's batches
    const int* __restrict__ cum_q,            // global chunk base per batch
    float* __restrict__ partial,
    const unsigned short* __restrict__ zp) {
  __shared__ unsigned short As[3 * 128 * 32]; // [t][c][ci]
  __shared__ unsigned short Bs[384 * 32];     // [row=p-3*s_base][ci]

  int tid = threadIdx.x;
  int wave = tid >> 6, lane = tid & 63;
  int cm = blockIdx.x * 128;
  int b = blockIdx.y / (SPAD / 128);          // batch-local (uniform per block)
  int s_base = (blockIdx.y % (SPAD / 128)) * 128;
  int slen = seq_q[b];
  if (3 * s_base + KW > slen) return;
  int p_base = 3 * s_base;
  int wm = (wave >> 1) * 64;
  int wn = (wave & 1) * 64;
  const size_t hb = (size_t)b * LSEQ * HCH;

  f32x4 acc[4][4] = {};

  int lr = lane >> 2, lc = (lane & 3) * 8;

  const unsigned short* bptr[6];
  const unsigned short* aptr[6];
  unsigned aoff[6];
  for (int t = 0; t < 6; t++) {
    int c = wave * 6 + t;
    int p = p_base + c * 16 + lr;
    bptr[t] = (p < LSEQ) ? (h2 + hb + (size_t)p * HCH + lc) : (zp + lc);
    int k = c >> 3, c8 = c & 7;
    aptr[t] = wTp + (size_t)(cm + c8 * 16 + lr) * KDIM + k * HCH + lc;
    aoff[t] = (unsigned)(k * 4096 + c8 * 512) * 2;
  }

  for (int it = 0; it < 16; it++) {
    int ci0 = it * 32;
    for (int t = 0; t < 6; t++) {
      gl_lds16(aptr[t] + ci0, (char*)As + aoff[t]);
      gl_lds16(bptr[t] + ci0, (char*)Bs + (wave * 6 + t) * 1024);
    }
    __syncthreads();

    int quad = lane >> 4, mr = lane & 15;
    for (int t = 0; t < 3; t++) {
      bf16x8 af[4], bfr[4];
      for (int i = 0; i < 4; i++)
        af[i] = *reinterpret_cast<const bf16x8*>(As + t * 4096 + (wm + i * 16 + mr) * 32 + quad * 8);
      for (int j = 0; j < 4; j++)
        bfr[j] = *reinterpret_cast<const bf16x8*>(Bs + (3 * (wn + j * 16 + mr) + t) * 32 + quad * 8);
      for (int i = 0; i < 4; i++)
        for (int j = 0; j < 4; j++)
          acc[i][j] = __builtin_amdgcn_mfma_f32_16x16x32_bf16(af[i], bfr[j], acc[i][j], 0, 0, 0);
    }
    __syncthreads();
  }

  // fused head: per column s, sum relu(z+pb)*fw over this block's 128 channels
  int quad = lane >> 4, nn = lane & 15;
  for (int j = 0; j < 4; j++) {
    float s = 0.f;
    for (int i = 0; i < 4; i++) {
      int c = cm + wm + i * 16 + quad * 4;
      f32x4 pbv = *reinterpret_cast<const f32x4*>(pb + c);
      f32x4 fwv = *reinterpret_cast<const f32x4*>(fw + c);
      for (int r = 0; r < 4; r++) {
        float z = acc[i][j][r] + pbv[r];
        z = fmaxf(z, 0.f);
        s += z * fwv[r];
      }
    }
    s += __shfl_xor(s, 16, 64);
    s += __shfl_xor(s, 32, 64);
    if (quad == 0) {
      int sc = s_base + wn + j * 16 + nn;
      if (3 * sc + KW <= slen) atomicAdd(partial + cum_q[b] + sc, s);
    }
  }
}

// ---- final: sigmoid(partial + fb) ----------------------------------------
__global__ void finalize(const float* __restrict__ partial, const float* __restrict__ fb,
                         float* __restrict__ out, int n) {
  int i = blockIdx.x * 256 + threadIdx.x;
  if (i < n) {
    float t = partial[i] + fb[0];
    out[i] = 1.f / (1.f + expf(-t));
  }
}

extern "C" void kernel_launch(void* const* d_in, const int* in_sizes, int n_in,
                              void* d_out, int out_size, void* d_ws, size_t ws_size,
                              hipStream_t stream) {
  (void)in_sizes; (void)n_in;
  const float* x   = (const float*)d_in[0];
  const float* w0  = (const float*)d_in[1];
  const float* b0  = (const float*)d_in[2];
  const float* g0  = (const float*)d_in[3];
  const float* be0 = (const float*)d_in[4];
  const float* w1  = (const float*)d_in[5];
  const float* b1  = (const float*)d_in[6];
  const float* g1  = (const float*)d_in[7];
  const float* be1 = (const float*)d_in[8];
  const float* w2  = (const float*)d_in[9];
  const float* b2  = (const float*)d_in[10];
  const float* g2  = (const float*)d_in[11];
  const float* be2 = (const float*)d_in[12];
  const float* pw  = (const float*)d_in[13];
  const float* pb  = (const float*)d_in[14];
  const float* fw  = (const float*)d_in[15];
  const float* fb  = (const float*)d_in[16];
  const int* seq_lens = (const int*)d_in[17];

  char* ws = (char*)d_ws;
  unsigned short* zeropage = (unsigned short*)ws;          // 4096 B, zeroed
  float* partial = (float*)(ws + 4096);                    // out_size floats, zeroed
  size_t off = 4096 + (size_t)out_size * 4;
  off = (off + 255) & ~(size_t)255;
  int* cum = (int*)(ws + off);                             // NB ints
  off += NB * 4;
  off = (off + 255) & ~(size_t)255;
  unsigned short* wt = (unsigned short*)(ws + off);        // 3 x 512 x 1536 bf16
  off += (size_t)3 * HCH * KDIM * 2;
  off = (off + 255) & ~(size_t)255;
  size_t fixed = off;

  // pick largest power-of-two batches-per-pass whose 2 ping-pong buffers fit
  const size_t per_batch = (size_t)LSEQ * HCH * 2;         // 4 MiB
  int nb_pass = NB;
  while (nb_pass > 1 && fixed + 2 * per_batch * (size_t)nb_pass > ws_size)
    nb_pass >>= 1;
  unsigned short* h0 = (unsigned short*)(ws + fixed);
  unsigned short* h1 = h0 + (size_t)nb_pass * LSEQ * HCH;

  int nzero = 1024 + out_size;   // zeropage (1024 floats) + partial
  prep_all<<<(3 * HCH * KDIM) / 256, 256, 0, stream>>>(w1, w2, pw, wt, seq_lens, cum,
                                                       (float*)ws, nzero);

  int npass = NB / nb_pass;
  for (int q = 0; q < npass; q++) {
    const float* xq = x + (size_t)q * nb_pass * LSEQ;
    const int* sq = seq_lens + q * nb_pass;
    int nwg = nb_pass * 32;                  // 2 M-tiles x 16 N-tiles per batch
    layer0<<<nb_pass * (LSEQ / 32), 256, 0, stream>>>(xq, w0, b0, g0, be0, h0, sq);
    conv_gemm8<<<nwg, 512, 0, stream>>>(h0, wt, b1, g1, be1, h1, zeropage, sq, 1);
    conv_gemm8<<<nwg, 512, 0, stream>>>(h1, wt + (size_t)HCH * KDIM, b2, g2, be2, h0,
                                        zeropage, sq, 0);
    chunk_gemm<<<dim3(4, nb_pass * (SPAD / 128)), 256, 0, stream>>>(
        h0, wt + (size_t)2 * HCH * KDIM, pb, fw,
        sq, cum + q * nb_pass, partial, zeropage);
  }
  finalize<<<(out_size + 255) / 256, 256, 0, stream>>>(partial, fb, (float*)d_out, out_size);
}

// Round 3
// 599.409 us; speedup vs baseline: 1.0763x; 1.0250x over previous
//
#include <hip/hip_runtime.h>

#define HCH 512      // channels
#define LSEQ 4096    // sequence length
#define HSTR (LSEQ + 4)  // padded row stride: 1 front pad + 3 back pad rows
#define NB 32        // batch
#define KW 3         // conv kernel width
#define KDIM 1536    // HCH*KW, GEMM K
#define SPAD 1408    // padded chunk slots per sequence (max 1365), 11*128
#define INVS 0.9999950000374997f  // 1/sqrt(1+1e-5)
#define NT 24        // conv GEMM K-steps of 64

typedef __attribute__((ext_vector_type(8))) short bf16x8;
typedef __attribute__((ext_vector_type(4))) float f32x4;

__device__ inline unsigned short f2bf(float f) {
  unsigned int u = __float_as_uint(f);
  u += 0x7fffu + ((u >> 16) & 1u);
  return (unsigned short)(u >> 16);
}

__device__ inline void gl_lds16(const void* g, void* l) {
  __builtin_amdgcn_global_load_lds(
      (const __attribute__((address_space(1))) void*)g,
      (__attribute__((address_space(3))) void*)l, 16, 0, 0);
}

// ---- fused prep: zero zeropage+partial+h-pads, chunk prefix sum, w transpose
__global__ void prep_all(const float* __restrict__ w1, const float* __restrict__ w2,
                         const float* __restrict__ pw, unsigned short* __restrict__ wt,
                         const int* __restrict__ seq_lens, int* __restrict__ cum,
                         float* __restrict__ pz, int nz,
                         unsigned short* __restrict__ hbuf, int nbp) {
  int idx = blockIdx.x * 256 + threadIdx.x;
  if (idx < nz) pz[idx] = 0.f;
  if (idx == 0) {
    int acc = 0;
    for (int b = 0; b < NB; b++) {
      cum[b] = acc;
      acc += (seq_lens[b] - KW) / KW + 1;
    }
  }
  // zero pad rows of both h ping-pong buffers: rows {0, 4097, 4098, 4099}/batch
  int npads = 2 * nbp * 4 * HCH;
  if (idx < npads) {
    int per = nbp * 4 * HCH;
    int buf = idx / per, r = idx % per;
    int b = r / (4 * HCH), rr = r % (4 * HCH);
    int j = rr / HCH, c = rr % HCH;
    int row = (j == 0) ? 0 : (LSEQ + j);
    hbuf[((size_t)buf * nbp + b) * HSTR * HCH + (size_t)row * HCH + c] = 0;
  }
  if (idx < 3 * HCH * KDIM) {
    int which = idx / (HCH * KDIM);
    int r = idx % (HCH * KDIM);
    int c = r / KDIM;
    int rem = r % KDIM;
    int k = rem / HCH, ci = rem % HCH;
    const float* src = (which == 0) ? w1 : ((which == 1) ? w2 : pw);
    wt[idx] = f2bf(src[c * KDIM + ci * KW + k]);
  }
}

// ---- layer 0: 1->512 conv + relu + scale/shift, fp32 in, bf16 (b,row,C) out
__global__ void layer0(const float* __restrict__ x, const float* __restrict__ w0,
                       const float* __restrict__ b0, const float* __restrict__ g0,
                       const float* __restrict__ be0, unsigned short* __restrict__ h0,
                       const int* __restrict__ seq_q) {
  int tid = threadIdx.x;
  int wave = tid >> 6, lane = tid & 63;
  int pos0 = (blockIdx.x * 4 + wave) * 8;      // flattened (b_local*4096 + l)
  int l0 = pos0 & (LSEQ - 1);
  int bq = pos0 >> 12;
  if (l0 >= seq_q[bq] + 2) return;             // h0 needed only for l <= slen+1
  int c0 = lane * 8;

  float w[24], bb[8], gg[8], ee[8];
  for (int v = 0; v < 6; v++)
    *reinterpret_cast<float4*>(w + v * 4) = *reinterpret_cast<const float4*>(w0 + c0 * 3 + v * 4);
  for (int v = 0; v < 2; v++) {
    *reinterpret_cast<float4*>(bb + v * 4) = *reinterpret_cast<const float4*>(b0 + c0 + v * 4);
    *reinterpret_cast<float4*>(gg + v * 4) = *reinterpret_cast<const float4*>(g0 + c0 + v * 4);
    *reinterpret_cast<float4*>(ee + v * 4) = *reinterpret_cast<const float4*>(be0 + c0 + v * 4);
  }
  for (int c = 0; c < 8; c++) gg[c] *= INVS;

  const float* xb = x + (size_t)(pos0 - l0);   // batch base
  unsigned short* hrow = h0 + ((size_t)bq * HSTR + 1 + l0) * HCH + c0;
  for (int pp = 0; pp < 8; pp++) {
    int l = l0 + pp;
    float xm1 = (l > 0) ? xb[l - 1] : 0.f;
    float xc = xb[l];
    float xp1 = (l < LSEQ - 1) ? xb[l + 1] : 0.f;
    unsigned int o[4];
    for (int pq = 0; pq < 4; pq++) {
      unsigned int lo = 0, hi = 0;
      for (int s = 0; s < 2; s++) {
        int c = pq * 2 + s;
        float y = w[c * 3] * xm1 + w[c * 3 + 1] * xc + w[c * 3 + 2] * xp1 + bb[c];
        y = fmaxf(y, 0.f);
        unsigned int u = f2bf(gg[c] * y + ee[c]);
        if (s == 0) lo = u; else hi = u;
      }
      o[pq] = lo | (hi << 16);
    }
    uint4 v4; v4.x = o[0]; v4.y = o[1]; v4.z = o[2]; v4.w = o[3];
    *reinterpret_cast<uint4*>(hrow + (size_t)pp * HCH) = v4;
  }
}

// ---- conv layer as 256x256 GEMM, 3-deep B pipeline, 1 barrier/K-step -----
// K-step t: k = t%3, ci0 = (t/3)*64  (k-inner => L2-hot k-slice reuse).
// LDS 160 KiB: A 2 x 32 KB dbuf + B 3 x 32 KB tbuf.  All staging offsets
// compile-time (full 24-step unroll, padded h => no predication).
// Waits: per step, WAITV(4) BEFORE barrier forces the 8 oldest loads
// (= B(t) issued t-2, A(t) issued t-1) complete in EVERY wave -> after
// the barrier all waves' stages for step t are landed (race-free).
// B cover = 2 K-steps > HBM latency; A cover = 1 K-step > L2 latency.
#define OFFK(T) (((T) % 3) * HCH + ((T) / 3) * 64)

#define STAGE_A(Mh, AB, TN)                                                 \
  { char* d_ = ldsc + (AB) * 32768 + (Mh) * 16384 + w * 1024;               \
    gl_lds16(aSrc[Mh][0] + OFFK(TN), d_);                                   \
    gl_lds16(aSrc[Mh][1] + OFFK(TN), d_ + 8192); }

#define STAGE_B(Nh, BB, TN)                                                 \
  { char* d_ = ldsc + 65536 + (BB) * 32768 + (Nh) * 16384 + w * 1024;       \
    gl_lds16(bSrc[Nh][0] + OFFK(TN), d_);                                   \
    gl_lds16(bSrc[Nh][1] + OFFK(TN), d_ + 8192); }

#define LOAD_AF(Mh, AB)                                                     \
  _Pragma("unroll") for (int i_ = 0; i_ < 4; ++i_)                          \
  _Pragma("unroll") for (int s_ = 0; s_ < 2; ++s_)                          \
    af[i_][s_] = *reinterpret_cast<const bf16x8*>(                          \
        ldsb + (AB) * 16384 + (Mh) * 8192 + (wm + i_ * 16 + mr) * 64 +      \
        (((s_ * 4 + quad) ^ (mr & 7)) << 3));

#define LOAD_BF(Nh, BB)                                                     \
  _Pragma("unroll") for (int j_ = 0; j_ < 2; ++j_)                          \
  _Pragma("unroll") for (int s_ = 0; s_ < 2; ++s_)                          \
    bfv[Nh][j_][s_] = *reinterpret_cast<const bf16x8*>(                     \
        ldsb + 32768 + (BB) * 16384 + (Nh) * 8192 + (wn + j_ * 16 + mr) * 64 + \
        (((s_ * 4 + quad) ^ (mr & 7)) << 3));

#define MFMA_Q(Mh, Nh)                                                      \
  __builtin_amdgcn_s_setprio(1);                                            \
  _Pragma("unroll") for (int i_ = 0; i_ < 4; ++i_)                          \
  _Pragma("unroll") for (int j_ = 0; j_ < 2; ++j_)                          \
  _Pragma("unroll") for (int s_ = 0; s_ < 2; ++s_)                          \
    acc[(Mh)*4 + i_][(Nh)*2 + j_] = __builtin_amdgcn_mfma_f32_16x16x32_bf16( \
        af[i_][s_], bfv[Nh][j_][s_], acc[(Mh)*4 + i_][(Nh)*2 + j_], 0, 0, 0); \
  __builtin_amdgcn_s_setprio(0);

#define BARRIER { asm volatile("" ::: "memory");                            \
                  __builtin_amdgcn_s_barrier();                             \
                  asm volatile("" ::: "memory"); }
#define WAITV(n) asm volatile("s_waitcnt vmcnt(" #n ")" ::: "memory");

#define STEP(T)                                                             \
  {                                                                         \
    if ((T) == NT - 1) { WAITV(0); } else { WAITV(4); }                     \
    BARRIER;                                                                \
    if ((T) + 1 < NT) { STAGE_A(0, ((T)+1)&1, (T)+1);                       \
                        STAGE_A(1, ((T)+1)&1, (T)+1); }                     \
    if ((T) + 2 < NT) { STAGE_B(0, ((T)+2)%3, (T)+2);                       \
                        STAGE_B(1, ((T)+2)%3, (T)+2); }                     \
    bf16x8 af[4][2], bfv[2][2][2];                                          \
    LOAD_AF(0, (T)&1);                                                      \
    LOAD_BF(0, (T)%3); LOAD_BF(1, (T)%3);                                   \
    MFMA_Q(0, 0); MFMA_Q(0, 1);                                             \
    LOAD_AF(1, (T)&1);                                                      \
    MFMA_Q(1, 1); MFMA_Q(1, 0);                                             \
  }

__global__ __launch_bounds__(512, 2) void conv_gemm8(
    const unsigned short* __restrict__ hin,   // (nb,HSTR,C) bf16, padded
    const unsigned short* __restrict__ wT,    // (512, 1536) bf16 A-layout
    const float* __restrict__ bconv, const float* __restrict__ g,
    const float* __restrict__ be,
    unsigned short* __restrict__ hout,        // (nb,HSTR,C) bf16, padded
    const int* __restrict__ seq_q, int margin) {
  __shared__ unsigned short ldsb[81920];      // 160 KiB: A 64 KB + B 96 KB

  // T1: bijective XCD-chunk swizzle; pairs (cm 0/256 of same tile) same XCD
  int f = blockIdx.x;
  int cpx = gridDim.x >> 3;                   // gridDim.x % 8 == 0 by launch
  int s = (f & 7) * cpx + (f >> 3);
  int cm = (s & 1) << 8;                      // out-channel tile: 0 or 256
  int y = s >> 1;
  int b = y >> 4;                             // batch-local
  int l0 = (y & 15) << 8;                     // 256-position tile
  int limit = seq_q[b] + margin;              // outputs needed for n < limit
  if (l0 >= limit) return;                    // block-uniform, pre-barrier

  const size_t hb = (size_t)b * HSTR * HCH + HCH;  // +1 row front pad
  int tid = threadIdx.x;
  int w = tid >> 6, lane = tid & 63;
  int quad = lane >> 4, mr = lane & 15;
  int wm = (w >> 2) << 6;                     // 0/64 within A half
  int wn = (w & 3) << 5;                      // 0/32/64/96 within B half
  int srow = tid >> 3;                        // staging row 0..63 within group
  int sslot8 = (((tid & 7) ^ (srow & 7)) << 3);  // swizzled src offset (shorts)

  // A sources [Mh][row-group]: wT row = channel, contiguous K
  const unsigned short* aSrc[2][2];
#pragma unroll
  for (int Mh = 0; Mh < 2; ++Mh)
#pragma unroll
    for (int g2 = 0; g2 < 2; ++g2)
      aSrc[Mh][g2] = wT + (size_t)(cm + Mh * 128 + g2 * 64 + srow) * KDIM + sslot8;
  // B sources [Nh][row-group]: k=0 window starts at position l0-1 (pad-safe)
  const unsigned short* bSrc[2][2];
#pragma unroll
  for (int Nh = 0; Nh < 2; ++Nh)
#pragma unroll
    for (int g2 = 0; g2 < 2; ++g2)
      bSrc[Nh][g2] = hin + hb +
          (size_t)(l0 - 1 + Nh * 128 + g2 * 64 + srow) * HCH + sslot8;

  f32x4 acc[8][4] = {};
  char* ldsc = (char*)ldsb;

  // prologue: A(0)->a0, B(0)->b0, B(1)->b1  (12 outstanding, oldest 8 = A0+B0)
  STAGE_A(0, 0, 0); STAGE_A(1, 0, 0);
  STAGE_B(0, 0, 0); STAGE_B(1, 0, 0);
  STAGE_B(0, 1, 1); STAGE_B(1, 1, 1);

  STEP(0)  STEP(1)  STEP(2)  STEP(3)  STEP(4)  STEP(5)
  STEP(6)  STEP(7)  STEP(8)  STEP(9)  STEP(10) STEP(11)
  STEP(12) STEP(13) STEP(14) STEP(15) STEP(16) STEP(17)
  STEP(18) STEP(19) STEP(20) STEP(21) STEP(22) STEP(23)

  // epilogue: relu(acc + b) * g*inv + be -> bf16; C/D: col=lane&15, row=quad*4+r
#pragma unroll
  for (int ai = 0; ai < 8; ++ai) {
    int Mh = ai >> 2, i = ai & 3;
    int c = cm + Mh * 128 + wm + i * 16 + quad * 4;
    f32x4 bc = *reinterpret_cast<const f32x4*>(bconv + c);
    f32x4 gg = *reinterpret_cast<const f32x4*>(g + c);
    f32x4 bb = *reinterpret_cast<const f32x4*>(be + c);
#pragma unroll
    for (int aj = 0; aj < 4; ++aj) {
      int Nh = aj >> 1, j = aj & 1;
      int n = l0 + Nh * 128 + wn + j * 16 + (lane & 15);
      if (n >= limit) continue;
      unsigned long long pack = 0;
#pragma unroll
      for (int r = 0; r < 4; ++r) {
        float yv = acc[ai][aj][r] + bc[r];
        yv = fmaxf(yv, 0.f);
        unsigned long long u = f2bf(gg[r] * INVS * yv + bb[r]);
        pack |= u << (16 * r);
      }
      *reinterpret_cast<unsigned long long*>(hout + hb + (size_t)n * HCH + c) = pack;
    }
  }
}

// ---- chunk einsum GEMM + fused head (padded-h addressing) ----------------
__global__ __launch_bounds__(256) void chunk_gemm(
    const unsigned short* __restrict__ h2,    // (nb,HSTR,C) bf16, padded
    const unsigned short* __restrict__ wTp,   // (512,1536) bf16 A-layout
    const float* __restrict__ pb, const float* __restrict__ fw,
    const int* __restrict__ seq_q,            // seq_lens for this pass's batches
    const int* __restrict__ cum_q,            // global chunk base per batch
    float* __restrict__ partial,
    const unsigned short* __restrict__ zp) {
  __shared__ unsigned short As[3 * 128 * 32]; // [t][c][ci]
  __shared__ unsigned short Bs[384 * 32];     // [row=p-3*s_base][ci]

  int tid = threadIdx.x;
  int wave = tid >> 6, lane = tid & 63;
  int cm = blockIdx.x * 128;
  int b = blockIdx.y / (SPAD / 128);          // batch-local (uniform per block)
  int s_base = (blockIdx.y % (SPAD / 128)) * 128;
  int slen = seq_q[b];
  if (3 * s_base + KW > slen) return;
  int p_base = 3 * s_base;
  int wm = (wave >> 1) * 64;
  int wn = (wave & 1) * 64;
  const size_t hb = (size_t)b * HSTR * HCH + HCH;

  f32x4 acc[4][4] = {};

  int lr = lane >> 2, lc = (lane & 3) * 8;

  const unsigned short* bptr[6];
  const unsigned short* aptr[6];
  unsigned aoff[6];
  for (int t = 0; t < 6; t++) {
    int c = wave * 6 + t;
    int p = p_base + c * 16 + lr;
    bptr[t] = (p < LSEQ) ? (h2 + hb + (size_t)p * HCH + lc) : (zp + lc);
    int k = c >> 3, c8 = c & 7;
    aptr[t] = wTp + (size_t)(cm + c8 * 16 + lr) * KDIM + k * HCH + lc;
    aoff[t] = (unsigned)(k * 4096 + c8 * 512) * 2;
  }

  for (int it = 0; it < 16; it++) {
    int ci0 = it * 32;
    for (int t = 0; t < 6; t++) {
      gl_lds16(aptr[t] + ci0, (char*)As + aoff[t]);
      gl_lds16(bptr[t] + ci0, (char*)Bs + (wave * 6 + t) * 1024);
    }
    __syncthreads();

    int quad = lane >> 4, mr = lane & 15;
    for (int t = 0; t < 3; t++) {
      bf16x8 af[4], bfr[4];
      for (int i = 0; i < 4; i++)
        af[i] = *reinterpret_cast<const bf16x8*>(As + t * 4096 + (wm + i * 16 + mr) * 32 + quad * 8);
      for (int j = 0; j < 4; j++)
        bfr[j] = *reinterpret_cast<const bf16x8*>(Bs + (3 * (wn + j * 16 + mr) + t) * 32 + quad * 8);
      for (int i = 0; i < 4; i++)
        for (int j = 0; j < 4; j++)
          acc[i][j] = __builtin_amdgcn_mfma_f32_16x16x32_bf16(af[i], bfr[j], acc[i][j], 0, 0, 0);
    }
    __syncthreads();
  }

  // fused head: per column s, sum relu(z+pb)*fw over this block's 128 channels
  int quad = lane >> 4, nn = lane & 15;
  for (int j = 0; j < 4; j++) {
    float s = 0.f;
    for (int i = 0; i < 4; i++) {
      int c = cm + wm + i * 16 + quad * 4;
      f32x4 pbv = *reinterpret_cast<const f32x4*>(pb + c);
      f32x4 fwv = *reinterpret_cast<const f32x4*>(fw + c);
      for (int r = 0; r < 4; r++) {
        float z = acc[i][j][r] + pbv[r];
        z = fmaxf(z, 0.f);
        s += z * fwv[r];
      }
    }
    s += __shfl_xor(s, 16, 64);
    s += __shfl_xor(s, 32, 64);
    if (quad == 0) {
      int sc = s_base + wn + j * 16 + nn;
      if (3 * sc + KW <= slen) atomicAdd(partial + cum_q[b] + sc, s);
    }
  }
}

// ---- final: sigmoid(partial + fb) ----------------------------------------
__global__ void finalize(const float* __restrict__ partial, const float* __restrict__ fb,
                         float* __restrict__ out, int n) {
  int i = blockIdx.x * 256 + threadIdx.x;
  if (i < n) {
    float t = partial[i] + fb[0];
    out[i] = 1.f / (1.f + expf(-t));
  }
}

extern "C" void kernel_launch(void* const* d_in, const int* in_sizes, int n_in,
                              void* d_out, int out_size, void* d_ws, size_t ws_size,
                              hipStream_t stream) {
  (void)in_sizes; (void)n_in;
  const float* x   = (const float*)d_in[0];
  const float* w0  = (const float*)d_in[1];
  const float* b0  = (const float*)d_in[2];
  const float* g0  = (const float*)d_in[3];
  const float* be0 = (const float*)d_in[4];
  const float* w1  = (const float*)d_in[5];
  const float* b1  = (const float*)d_in[6];
  const float* g1  = (const float*)d_in[7];
  const float* be1 = (const float*)d_in[8];
  const float* w2  = (const float*)d_in[9];
  const float* b2  = (const float*)d_in[10];
  const float* g2  = (const float*)d_in[11];
  const float* be2 = (const float*)d_in[12];
  const float* pw  = (const float*)d_in[13];
  const float* pb  = (const float*)d_in[14];
  const float* fw  = (const float*)d_in[15];
  const float* fb  = (const float*)d_in[16];
  const int* seq_lens = (const int*)d_in[17];

  char* ws = (char*)d_ws;
  unsigned short* zeropage = (unsigned short*)ws;          // 4096 B, zeroed
  float* partial = (float*)(ws + 4096);                    // out_size floats, zeroed
  size_t off = 4096 + (size_t)out_size * 4;
  off = (off + 255) & ~(size_t)255;
  int* cum = (int*)(ws + off);                             // NB ints
  off += NB * 4;
  off = (off + 255) & ~(size_t)255;
  unsigned short* wt = (unsigned short*)(ws + off);        // 3 x 512 x 1536 bf16
  off += (size_t)3 * HCH * KDIM * 2;
  off = (off + 255) & ~(size_t)255;
  size_t fixed = off;

  // pick largest power-of-two batches-per-pass whose 2 ping-pong buffers fit
  const size_t per_batch = (size_t)HSTR * HCH * 2;         // padded, ~4.2 MiB
  int nb_pass = NB;
  while (nb_pass > 1 && fixed + 2 * per_batch * (size_t)nb_pass > ws_size)
    nb_pass >>= 1;
  unsigned short* h0 = (unsigned short*)(ws + fixed);
  unsigned short* h1 = h0 + (size_t)nb_pass * HSTR * HCH;

  int nzero = 1024 + out_size;   // zeropage (1024 floats) + partial
  prep_all<<<(3 * HCH * KDIM) / 256, 256, 0, stream>>>(w1, w2, pw, wt, seq_lens, cum,
                                                       (float*)ws, nzero, h0, nb_pass);

  int npass = NB / nb_pass;
  for (int q = 0; q < npass; q++) {
    const float* xq = x + (size_t)q * nb_pass * LSEQ;
    const int* sq = seq_lens + q * nb_pass;
    int nwg = nb_pass * 32;                  // 2 M-tiles x 16 N-tiles per batch
    layer0<<<nb_pass * (LSEQ / 32), 256, 0, stream>>>(xq, w0, b0, g0, be0, h0, sq);
    conv_gemm8<<<nwg, 512, 0, stream>>>(h0, wt, b1, g1, be1, h1, sq, 1);
    conv_gemm8<<<nwg, 512, 0, stream>>>(h1, wt + (size_t)HCH * KDIM, b2, g2, be2, h0,
                                        sq, 0);
    chunk_gemm<<<dim3(4, nb_pass * (SPAD / 128)), 256, 0, stream>>>(
        h0, wt + (size_t)2 * HCH * KDIM, pb, fw,
        sq, cum + q * nb_pass, partial, zeropage);
  }
  finalize<<<(out_size + 255) / 256, 256, 0, stream>>>(partial, fb, (float*)d_out, out_size);
}